// Round 17
// baseline (4412.438 us; speedup 1.0000x reference)
//
#include <hip/hip_runtime.h>

#define Tn 512
#define In 40
#define Hn 256
#define Kn 4
#define On 16
#define ROWS 16
#define NBLK 64

typedef _Float16 half8  __attribute__((ext_vector_type(8)));
typedef _Float16 half2v __attribute__((ext_vector_type(2)));
typedef float    f32x4  __attribute__((ext_vector_type(4)));

union UH { uint4 u; half8 h; half2v h2[4]; };

static __device__ __forceinline__ float tanh_fast(float x) {
    float e = __expf(2.f * x);
    return 1.f - 2.f * __builtin_amdgcn_rcpf(e + 1.f);
}

// async global->LDS, 16B per lane (prologue staging only)
static __device__ __forceinline__ void gll16(const void* g, void* l) {
    __builtin_amdgcn_global_load_lds(
        (const __attribute__((address_space(1))) void*)g,
        (__attribute__((address_space(3))) void*)l, 16, 0, 0);
}

// raw barrier: drain LDS ops only; register loads (vmcnt) stay in flight
#define BAR() do { asm volatile("s_waitcnt lgkmcnt(0)" ::: "memory"); \
                   __builtin_amdgcn_s_barrier(); } while (0)

// ---------------------------------------------------------------------------
// B-fragment pack (R3/R8/R13-validated, byte-identical): frag f = w*80+s*8+t.
//   s = 0..1 : input K-slices (In=40 padded to 64 with zeros)
//   s = 2..9 : recurrent K-slices (j = (s-2)*32 ..)
// Lane l holds B[k=(l>>4)*8+j][n = w*128 + t*16 + (l&15)], 8 fp16 at
// WPB[(f*64 + l)*8].
// ---------------------------------------------------------------------------
__global__ void pack_frags(const float* __restrict__ Wr, const float* __restrict__ Wi,
                           _Float16* __restrict__ WPB) {
    const int f = blockIdx.x;          // 0..639
    const int l = threadIdx.x;         // 0..63
    const int w = f / 80;
    const int rem = f - w * 80;
    const int s = rem >> 3, t = rem & 7;
    const int n = w * 128 + t * 16 + (l & 15);
    const int kloc = (l >> 4) * 8;
    half8 v;
    if (s < 2) {
#pragma unroll
        for (int j = 0; j < 8; j++) {
            const int k = s * 32 + kloc + j;
            v[j] = (k < In) ? (_Float16)Wi[n * In + k] : (_Float16)0.f;
        }
    } else {
#pragma unroll
        for (int j = 0; j < 8; j++)
            v[j] = (_Float16)Wr[(size_t)n * Hn + (s - 2) * 32 + kloc + j];
    }
    *(half8*)(WPB + ((size_t)f * 64 + l) * 8) = v;
}

// ---------------------------------------------------------------------------
// R16/R13 template (validated 2.79 ms) with ONE delta: rec slices 2 and 3 are
// REGISTER-resident (wr2[8], wr3[8], loaded once in the prologue — 64 VGPR of
// weights). Rationale: with 143 KB LDS the backend's occupancy-derived VGPR
// budget is 256 (1 block/CU -> 2 waves/EU), so the extra residency should
// allocate instead of remat/spill (R4-R6's 128-cap was an artifact of their
// small-LDS 4-waves/EU occupancy target). Streamed beats shrink to b=8..31
// (slices 4..9): per-CU stream 512 -> 384 KB/step. MFMA sequence, operand
// values, and order unchanged -> absmax bit-identical (0.0078125).
// ---------------------------------------------------------------------------
__global__ __launch_bounds__(512) void diru_reg5(
    const float* __restrict__ x,
    const _Float16* __restrict__ WPB,
    const float* __restrict__ b_in, const float* __restrict__ b_rec,
    const float* __restrict__ W_gate, const float* __restrict__ b_gate,
    const float* __restrict__ W_fc, const float* __restrict__ b_fc,
    float* __restrict__ out)
{
    const int tid = threadIdx.x;
    const int l   = tid & 63;
    const int w   = tid >> 6;
    const int lm  = l & 15;
    const int lq  = l >> 4;
    const int b0  = blockIdx.x * ROWS;

    __shared__ _Float16 hh_s[ROWS * 256];              // 8 KB, swizzled
    __shared__ _Float16 xs_s[ROWS * 64];               // 2 KB, swizzled (pad->64)
    __shared__ _Float16 outs_s[ROWS * 1024];           // 32 KB, swizzled
    __shared__ float    red[8 * ROWS * 4];             // 2 KB
    __shared__ __align__(16) char rbi1_lds[8 * 8 * 1024];  // 64 KB slice-1 frags
    __shared__ __align__(16) char gate_lds[8 * 4 * 1024];  // 32 KB gate frags

    const half8* __restrict__ WPB8 = (const half8*)WPB;
    const char*  __restrict__ WPBc = (const char*)WPB;

    // ---- prologue: slice-1 input frags -> LDS (per-wave, gll16) ----
#pragma unroll
    for (int t8 = 0; t8 < 8; t8++)
        gll16(WPBc + (size_t)(w * 80 + 8 + t8) * 1024 + l * 16,
              rbi1_lds + (size_t)(w * 8 + t8) * 1024);

    // ---- slice-0 input frags + rec slices 2,3 -> registers ----
    half8 rb0[8], wr2[8], wr3[8];
#pragma unroll
    for (int t8 = 0; t8 < 8; t8++) {
        rb0[t8] = WPB8[(size_t)(w * 80 + 0 * 8 + t8) * 64 + l];
        wr2[t8] = WPB8[(size_t)(w * 80 + 2 * 8 + t8) * 64 + l];   // rec slice 2
        wr3[t8] = WPB8[(size_t)(w * 80 + 3 * 8 + t8) * 64 + l];   // rec slice 3
    }

    // ---- gate B-frags -> LDS ----
#pragma unroll
    for (int s2 = 0; s2 < 4; s2++) {
        half8 g = {};
        if (lm < Kn) {
#pragma unroll
            for (int j = 0; j < 8; j++)
                g[j] = (_Float16)W_gate[lm * 1024 + w * 128 + s2 * 32 + lq * 8 + j];
        }
        *(half8*)(gate_lds + (size_t)(w * 4 + s2) * 1024 + l * 16) = g;
    }

    float bias[8];
#pragma unroll
    for (int t8 = 0; t8 < 8; t8++) {
        const int n = w * 128 + t8 * 16 + lm;
        bias[t8] = b_in[n] + b_rec[n];
    }
    float bg4[4];
#pragma unroll
    for (int kg = 0; kg < 4; kg++) bg4[kg] = b_gate[kg];

    // ---- zero hh/xs, stage x(0) ----
    for (int i = tid; i < ROWS * 256; i += 512) hh_s[i] = (_Float16)0.f;
    for (int i = tid; i < ROWS * 64;  i += 512) xs_s[i] = (_Float16)0.f;

    const int xi0_r = tid / In, xi0_i = tid - xi0_r * In;
    const int has2  = (tid + 512) < ROWS * In;     // tid < 128
    const int t1i   = tid + 512;
    const int xi1_r = t1i / In, xi1_i = t1i - xi1_r * In;
    const int xsb0 = xi0_r * 128 + (((((xi0_i * 2) >> 4) ^ (xi0_r & 7)) << 4) | ((xi0_i * 2) & 15));
    const int xsb1 = xi1_r * 128 + (((((xi1_i * 2) >> 4) ^ (xi1_r & 7)) << 4) | ((xi1_i * 2) & 15));
    const float* xp0 = x + ((size_t)(b0 + xi0_r) * Tn) * In + xi0_i;
    const float* xp1 = x + ((size_t)(b0 + xi1_r) * Tn) * In + xi1_i;
    *(_Float16*)((char*)xs_s + xsb0) = (_Float16)xp0[0];
    if (has2) *(_Float16*)((char*)xs_s + xsb1) = (_Float16)xp1[0];

    __syncthreads();   // prologue gll16 + LDS init drained and visible

    const int r_c  = tid >> 5;
    const int c32  = tid & 31;
    const int swzC = (r_c & 7);

    // streamed-fragment register buffers: 4 beats deep x 2 frags.
    half8 sb[4][2];

// issue beat b (slice 2+(b>>2), tiles (b&3)*2, (b&3)*2+1) into slot bi
#define ISSUE(b, bi) { \
    const int f0_ = w * 80 + (2 + ((b) >> 2)) * 8 + ((b) & 3) * 2; \
    sb[bi][0] = WPB8[(size_t)(f0_ + 0) * 64 + l]; \
    sb[bi][1] = WPB8[(size_t)(f0_ + 1) * 64 + l]; }

    for (int t = 0; t < Tn; t++) {
        // ---- x prefetch + first 4 streamed beats (8..11) issued before the
        //      barrier (register loads, legally in flight across BAR) ----
        float xr0 = 0.f, xr1 = 0.f;
        if (t + 1 < Tn) {
            xr0 = xp0[(size_t)(t + 1) * In];
            if (has2) xr1 = xp1[(size_t)(t + 1) * In];
        }
        ISSUE(8, 0); ISSUE(9, 1); ISSUE(10, 2); ISSUE(11, 3);

        BAR();   // hh(t), xs(t) ready

        f32x4 acc[8];
#pragma unroll
        for (int t8 = 0; t8 < 8; t8++) {
            f32x4 a; a[0] = bias[t8]; a[1] = bias[t8]; a[2] = bias[t8]; a[3] = bias[t8];
            acc[t8] = a;
        }

        // ---- input slices: s0 from registers, s1 from LDS-resident frags ----
        const half8 ax0 = *(const half8*)((const char*)xs_s + lm * 128 + (((0 + lq) ^ (lm & 7)) << 4));
        const half8 ax1 = *(const half8*)((const char*)xs_s + lm * 128 + (((4 + lq) ^ (lm & 7)) << 4));
#pragma unroll
        for (int t8 = 0; t8 < 8; t8++)
            acc[t8] = __builtin_amdgcn_mfma_f32_16x16x32_f16(ax0, rb0[t8], acc[t8], 0, 0, 0);
#pragma unroll
        for (int t8 = 0; t8 < 8; t8++) {
            const half8 bx = *(const half8*)(rbi1_lds + (size_t)(w * 8 + t8) * 1024 + l * 16);
            acc[t8] = __builtin_amdgcn_mfma_f32_16x16x32_f16(ax1, bx, acc[t8], 0, 0, 0);
        }

        // ---- rec slices: 32 beats; b<8 register-resident, b>=8 streamed ----
        half8 ah = {};
#pragma unroll
        for (int b = 0; b < 32; b++) {
            const int sIdx = b >> 2;               // rec slice 2+sIdx
            if ((b & 3) == 0)
                ah = *(const half8*)((const char*)hh_s + lm * 512
                                     + (((sIdx * 4 + lq) ^ (lm & 7)) << 4));
            half8 bf0, bf1;
            if (b < 4)      { bf0 = wr2[(b & 3) * 2]; bf1 = wr2[(b & 3) * 2 + 1]; }
            else if (b < 8) { bf0 = wr3[(b & 3) * 2]; bf1 = wr3[(b & 3) * 2 + 1]; }
            else            { bf0 = sb[b % 4][0];     bf1 = sb[b % 4][1]; }
            const int tA = (b & 3) * 2;
            acc[tA + 0] = __builtin_amdgcn_mfma_f32_16x16x32_f16(ah, bf0, acc[tA + 0], 0, 0, 0);
            acc[tA + 1] = __builtin_amdgcn_mfma_f32_16x16x32_f16(ah, bf1, acc[tA + 1], 0, 0, 0);
            if (b >= 8 && b + 4 <= 31) ISSUE(b + 4, (b + 4) % 4);
        }

        // ---- tanh + outs write (swizzled, wave-own cols) ----
#pragma unroll
        for (int t8 = 0; t8 < 8; t8++) {
            const int colb = w * 256 + t8 * 32 + lm * 2;
            const int slot = colb >> 4;
#pragma unroll
            for (int q = 0; q < 4; q++) {
                const int row = lq * 4 + q;
                *(_Float16*)((char*)outs_s + row * 2048 + (((slot ^ (row & 7)) << 4) | (colb & 15)))
                    = (_Float16)tanh_fast(acc[t8][q]);
            }
        }

        // ---- gate logits (wave-own outs chunk; gate frags from LDS) ----
        {
            f32x4 gacc = {0.f, 0.f, 0.f, 0.f};
#pragma unroll
            for (int s2 = 0; s2 < 4; s2++) {
                const int slot = w * 16 + s2 * 4 + lq;
                const half8 ga = *(const half8*)((const char*)outs_s + lm * 2048
                                                 + ((slot ^ (lm & 7)) << 4));
                const half8 gbl = *(const half8*)(gate_lds + (size_t)(w * 4 + s2) * 1024 + l * 16);
                gacc = __builtin_amdgcn_mfma_f32_16x16x32_f16(ga, gbl, gacc, 0, 0, 0);
            }
            if (lm < 4) {
#pragma unroll
                for (int q = 0; q < 4; q++)
                    red[(w * 16 + (lq * 4 + q)) * 4 + lm] = gacc[q];
            }
        }

        BAR();   // outs + red visible to all waves

        // ---- softmax + h_new + x stage ----
        {
            float lg0 = bg4[0], lg1 = bg4[1], lg2 = bg4[2], lg3 = bg4[3];
#pragma unroll
            for (int w2 = 0; w2 < 8; w2++) {
                const f32x4 v = *(const f32x4*)&red[(w2 * 16 + r_c) * 4];
                lg0 += v[0]; lg1 += v[1]; lg2 += v[2]; lg3 += v[3];
            }
            const float mx = fmaxf(fmaxf(lg0, lg1), fmaxf(lg2, lg3));
            const float e0 = __expf(lg0 - mx), e1 = __expf(lg1 - mx);
            const float e2 = __expf(lg2 - mx), e3 = __expf(lg3 - mx);
            const float inv = __builtin_amdgcn_rcpf(e0 + e1 + e2 + e3);
            half2v wg2[4];
            {
                const float wf[4] = { e0 * inv, e1 * inv, e2 * inv, e3 * inv };
#pragma unroll
                for (int k = 0; k < 4; k++) {
                    const _Float16 h = (_Float16)wf[k];
                    half2v v2; v2[0] = h; v2[1] = h; wg2[k] = v2;
                }
            }
            half2v hn[4] = {};
#pragma unroll
            for (int k = 0; k < 4; k++) {
                const int slot = k * 32 + c32;
                UH ov;
                ov.h = *(const half8*)((const char*)outs_s + r_c * 2048 + ((slot ^ swzC) << 4));
#pragma unroll
                for (int pp = 0; pp < 4; pp++)
                    hn[pp] = hn[pp] + ov.h2[pp] * wg2[k];
            }
            UH ho;
#pragma unroll
            for (int pp = 0; pp < 4; pp++) ho.h2[pp] = hn[pp];
            *(uint4*)((char*)hh_s + r_c * 512 + ((c32 ^ swzC) << 4)) = ho.u;
        }
        if (t + 1 < Tn) {
            *(_Float16*)((char*)xs_s + xsb0) = (_Float16)xr0;
            if (has2) *(_Float16*)((char*)xs_s + xsb1) = (_Float16)xr1;
        }
        // loop-top BAR orders hh/xs writes vs next step's reads
    }

    BAR();
    // ---- final FC ----
    if (tid < ROWS * On) {
        const int r = tid >> 4, o = tid & 15;
        float s = b_fc[o];
#pragma unroll 4
        for (int j8 = 0; j8 < 32; j8++) {
            const half8 hv = *(const half8*)((const char*)hh_s + r * 512 + ((j8 ^ (r & 7)) << 4));
#pragma unroll
            for (int jj = 0; jj < 8; jj++)
                s = fmaf((float)hv[jj], W_fc[o * Hn + j8 * 8 + jj], s);
        }
        out[(size_t)(b0 + r) * On + o] = s;
    }
#undef ISSUE
}

extern "C" void kernel_launch(void* const* d_in, const int* in_sizes, int n_in,
                              void* d_out, int out_size, void* d_ws, size_t ws_size,
                              hipStream_t stream) {
    const float* x      = (const float*)d_in[0];
    const float* W_in   = (const float*)d_in[1];
    const float* b_in   = (const float*)d_in[2];
    const float* W_rec  = (const float*)d_in[3];
    const float* b_rec  = (const float*)d_in[4];
    const float* W_gate = (const float*)d_in[5];
    const float* b_gate = (const float*)d_in[6];
    const float* W_fc   = (const float*)d_in[7];
    const float* b_fc   = (const float*)d_in[8];
    float* out = (float*)d_out;

    _Float16* WPB = (_Float16*)d_ws;   // 640 frags * 1 KB = 640 KB

    pack_frags<<<640, 64, 0, stream>>>(W_rec, W_in, WPB);
    diru_reg5<<<NBLK, 512, 0, stream>>>(x, WPB, b_in, b_rec,
                                        W_gate, b_gate, W_fc, b_fc, out);
}

// Round 18
// 2785.966 us; speedup vs baseline: 1.5838x; 1.5838x over previous
//
#include <hip/hip_runtime.h>

#define Tn 512
#define In 40
#define Hn 256
#define Kn 4
#define On 16
#define ROWS 16
#define NBLK 64

typedef _Float16 half8  __attribute__((ext_vector_type(8)));
typedef _Float16 half2v __attribute__((ext_vector_type(2)));
typedef float    f32x4  __attribute__((ext_vector_type(4)));

union UH { uint4 u; half8 h; half2v h2[4]; };

static __device__ __forceinline__ float tanh_fast(float x) {
    float e = __expf(2.f * x);
    return 1.f - 2.f * __builtin_amdgcn_rcpf(e + 1.f);
}

// async global->LDS, 16B per lane (prologue staging only)
static __device__ __forceinline__ void gll16(const void* g, void* l) {
    __builtin_amdgcn_global_load_lds(
        (const __attribute__((address_space(1))) void*)g,
        (__attribute__((address_space(3))) void*)l, 16, 0, 0);
}

// raw barrier: drain LDS ops only; register loads (vmcnt) stay in flight
#define BAR() do { asm volatile("s_waitcnt lgkmcnt(0)" ::: "memory"); \
                   __builtin_amdgcn_s_barrier(); } while (0)

// ---------------------------------------------------------------------------
// B-fragment pack (R3/R8/R13-validated, byte-identical): frag f = w*80+s*8+t.
//   s = 0..1 : input K-slices (In=40 padded to 64 with zeros)
//   s = 2..9 : recurrent K-slices (j = (s-2)*32 ..)
// Lane l holds B[k=(l>>4)*8+j][n = w*128 + t*16 + (l&15)], 8 fp16 at
// WPB[(f*64 + l)*8].
// ---------------------------------------------------------------------------
__global__ void pack_frags(const float* __restrict__ Wr, const float* __restrict__ Wi,
                           _Float16* __restrict__ WPB) {
    const int f = blockIdx.x;          // 0..639
    const int l = threadIdx.x;         // 0..63
    const int w = f / 80;
    const int rem = f - w * 80;
    const int s = rem >> 3, t = rem & 7;
    const int n = w * 128 + t * 16 + (l & 15);
    const int kloc = (l >> 4) * 8;
    half8 v;
    if (s < 2) {
#pragma unroll
        for (int j = 0; j < 8; j++) {
            const int k = s * 32 + kloc + j;
            v[j] = (k < In) ? (_Float16)Wi[n * In + k] : (_Float16)0.f;
        }
    } else {
#pragma unroll
        for (int j = 0; j < 8; j++)
            v[j] = (_Float16)Wr[(size_t)n * Hn + (s - 2) * 32 + kloc + j];
    }
    *(half8*)(WPB + ((size_t)f * 64 + l) * 8) = v;
}

// ---------------------------------------------------------------------------
// R13/R16 (validated 2.79 ms), byte-identical. Per-step weight stream is
// REGISTER-staged: global_load_dwordx4 -> named VGPR buffers sb[4][2] (WAR on
// the slot bounds register pressure and pipeline depth; compiler inserts
// precise vmcnt) -> MFMA directly. No gll16/stage[]/ds_read round-trip for
// streamed frags (wave-private; LDS staging was pure overhead). Slice-1
// input frags (64 KB) + gate frags (32 KB) LDS-resident (staged once);
// slice-0 input frags in registers. LDS total 140 KB.
// ---------------------------------------------------------------------------
__global__ __launch_bounds__(512) void diru_reg2(
    const float* __restrict__ x,
    const _Float16* __restrict__ WPB,
    const float* __restrict__ b_in, const float* __restrict__ b_rec,
    const float* __restrict__ W_gate, const float* __restrict__ b_gate,
    const float* __restrict__ W_fc, const float* __restrict__ b_fc,
    float* __restrict__ out)
{
    const int tid = threadIdx.x;
    const int l   = tid & 63;
    const int w   = tid >> 6;
    const int lm  = l & 15;
    const int lq  = l >> 4;
    const int b0  = blockIdx.x * ROWS;

    __shared__ _Float16 hh_s[ROWS * 256];              // 8 KB, swizzled
    __shared__ _Float16 xs_s[ROWS * 64];               // 2 KB, swizzled (pad->64)
    __shared__ _Float16 outs_s[ROWS * 1024];           // 32 KB, swizzled
    __shared__ float    red[8 * ROWS * 4];             // 2 KB
    __shared__ __align__(16) char rbi1_lds[8 * 8 * 1024];  // 64 KB slice-1 frags
    __shared__ __align__(16) char gate_lds[8 * 4 * 1024];  // 32 KB gate frags

    const half8* __restrict__ WPB8 = (const half8*)WPB;
    const char*  __restrict__ WPBc = (const char*)WPB;

    // ---- prologue: slice-1 input frags -> LDS (per-wave, gll16) ----
#pragma unroll
    for (int t8 = 0; t8 < 8; t8++)
        gll16(WPBc + (size_t)(w * 80 + 8 + t8) * 1024 + l * 16,
              rbi1_lds + (size_t)(w * 8 + t8) * 1024);

    // ---- slice-0 input frags -> registers ----
    half8 rb0[8];
#pragma unroll
    for (int t8 = 0; t8 < 8; t8++)
        rb0[t8] = WPB8[(size_t)(w * 80 + 0 * 8 + t8) * 64 + l];

    // ---- gate B-frags -> LDS ----
#pragma unroll
    for (int s2 = 0; s2 < 4; s2++) {
        half8 g = {};
        if (lm < Kn) {
#pragma unroll
            for (int j = 0; j < 8; j++)
                g[j] = (_Float16)W_gate[lm * 1024 + w * 128 + s2 * 32 + lq * 8 + j];
        }
        *(half8*)(gate_lds + (size_t)(w * 4 + s2) * 1024 + l * 16) = g;
    }

    float bias[8];
#pragma unroll
    for (int t8 = 0; t8 < 8; t8++) {
        const int n = w * 128 + t8 * 16 + lm;
        bias[t8] = b_in[n] + b_rec[n];
    }
    float bg4[4];
#pragma unroll
    for (int kg = 0; kg < 4; kg++) bg4[kg] = b_gate[kg];

    // ---- zero hh/xs, stage x(0) ----
    for (int i = tid; i < ROWS * 256; i += 512) hh_s[i] = (_Float16)0.f;
    for (int i = tid; i < ROWS * 64;  i += 512) xs_s[i] = (_Float16)0.f;

    const int xi0_r = tid / In, xi0_i = tid - xi0_r * In;
    const int has2  = (tid + 512) < ROWS * In;     // tid < 128
    const int t1i   = tid + 512;
    const int xi1_r = t1i / In, xi1_i = t1i - xi1_r * In;
    const int xsb0 = xi0_r * 128 + (((((xi0_i * 2) >> 4) ^ (xi0_r & 7)) << 4) | ((xi0_i * 2) & 15));
    const int xsb1 = xi1_r * 128 + (((((xi1_i * 2) >> 4) ^ (xi1_r & 7)) << 4) | ((xi1_i * 2) & 15));
    const float* xp0 = x + ((size_t)(b0 + xi0_r) * Tn) * In + xi0_i;
    const float* xp1 = x + ((size_t)(b0 + xi1_r) * Tn) * In + xi1_i;
    *(_Float16*)((char*)xs_s + xsb0) = (_Float16)xp0[0];
    if (has2) *(_Float16*)((char*)xs_s + xsb1) = (_Float16)xp1[0];

    __syncthreads();   // prologue gll16 + LDS init drained and visible

    const int r_c  = tid >> 5;
    const int c32  = tid & 31;
    const int swzC = (r_c & 7);

    // streamed-fragment register buffers: 4 beats deep x 2 frags.
    // Fully-unrolled constant indexing -> registers (rule #20 safe).
    half8 sb[4][2];

// issue beat b (slice 2+(b>>2), tiles (b&3)*2, (b&3)*2+1) into slot bi
#define ISSUE(b, bi) { \
    const int f0_ = w * 80 + (2 + ((b) >> 2)) * 8 + ((b) & 3) * 2; \
    sb[bi][0] = WPB8[(size_t)(f0_ + 0) * 64 + l]; \
    sb[bi][1] = WPB8[(size_t)(f0_ + 1) * 64 + l]; }

    for (int t = 0; t < Tn; t++) {
        // ---- x prefetch + first 4 beats issued before barrier (register
        //      loads, no LDS dependence -> legally in flight across BAR) ----
        float xr0 = 0.f, xr1 = 0.f;
        if (t + 1 < Tn) {
            xr0 = xp0[(size_t)(t + 1) * In];
            if (has2) xr1 = xp1[(size_t)(t + 1) * In];
        }
        ISSUE(0, 0); ISSUE(1, 1); ISSUE(2, 2); ISSUE(3, 3);

        BAR();   // hh(t), xs(t) ready

        f32x4 acc[8];
#pragma unroll
        for (int t8 = 0; t8 < 8; t8++) {
            f32x4 a; a[0] = bias[t8]; a[1] = bias[t8]; a[2] = bias[t8]; a[3] = bias[t8];
            acc[t8] = a;
        }

        // ---- input slices: s0 from registers, s1 from LDS-resident frags ----
        const half8 ax0 = *(const half8*)((const char*)xs_s + lm * 128 + (((0 + lq) ^ (lm & 7)) << 4));
        const half8 ax1 = *(const half8*)((const char*)xs_s + lm * 128 + (((4 + lq) ^ (lm & 7)) << 4));
#pragma unroll
        for (int t8 = 0; t8 < 8; t8++)
            acc[t8] = __builtin_amdgcn_mfma_f32_16x16x32_f16(ax0, rb0[t8], acc[t8], 0, 0, 0);
#pragma unroll
        for (int t8 = 0; t8 < 8; t8++) {
            const half8 bx = *(const half8*)(rbi1_lds + (size_t)(w * 8 + t8) * 1024 + l * 16);
            acc[t8] = __builtin_amdgcn_mfma_f32_16x16x32_f16(ax1, bx, acc[t8], 0, 0, 0);
        }

        // ---- streamed rec slices: 32 beats x 2 frags, reg-staged ----
        half8 ah = {};
#pragma unroll
        for (int b = 0; b < 32; b++) {
            const int sIdx = b >> 2;               // rec slice 2+sIdx
            if ((b & 3) == 0)
                ah = *(const half8*)((const char*)hh_s + lm * 512
                                     + (((sIdx * 4 + lq) ^ (lm & 7)) << 4));
            const int tA = (b & 3) * 2;
            acc[tA + 0] = __builtin_amdgcn_mfma_f32_16x16x32_f16(ah, sb[b % 4][0], acc[tA + 0], 0, 0, 0);
            acc[tA + 1] = __builtin_amdgcn_mfma_f32_16x16x32_f16(ah, sb[b % 4][1], acc[tA + 1], 0, 0, 0);
            if (b + 4 <= 31) ISSUE(b + 4, (b + 4) % 4);
        }

        // ---- tanh + outs write (swizzled, wave-own cols) ----
#pragma unroll
        for (int t8 = 0; t8 < 8; t8++) {
            const int colb = w * 256 + t8 * 32 + lm * 2;
            const int slot = colb >> 4;
#pragma unroll
            for (int q = 0; q < 4; q++) {
                const int row = lq * 4 + q;
                *(_Float16*)((char*)outs_s + row * 2048 + (((slot ^ (row & 7)) << 4) | (colb & 15)))
                    = (_Float16)tanh_fast(acc[t8][q]);
            }
        }

        // ---- gate logits (wave-own outs chunk; gate frags from LDS) ----
        {
            f32x4 gacc = {0.f, 0.f, 0.f, 0.f};
#pragma unroll
            for (int s2 = 0; s2 < 4; s2++) {
                const int slot = w * 16 + s2 * 4 + lq;
                const half8 ga = *(const half8*)((const char*)outs_s + lm * 2048
                                                 + ((slot ^ (lm & 7)) << 4));
                const half8 gbl = *(const half8*)(gate_lds + (size_t)(w * 4 + s2) * 1024 + l * 16);
                gacc = __builtin_amdgcn_mfma_f32_16x16x32_f16(ga, gbl, gacc, 0, 0, 0);
            }
            if (lm < 4) {
#pragma unroll
                for (int q = 0; q < 4; q++)
                    red[(w * 16 + (lq * 4 + q)) * 4 + lm] = gacc[q];
            }
        }

        BAR();   // outs + red visible to all waves

        // ---- softmax + h_new + x stage ----
        {
            float lg0 = bg4[0], lg1 = bg4[1], lg2 = bg4[2], lg3 = bg4[3];
#pragma unroll
            for (int w2 = 0; w2 < 8; w2++) {
                const f32x4 v = *(const f32x4*)&red[(w2 * 16 + r_c) * 4];
                lg0 += v[0]; lg1 += v[1]; lg2 += v[2]; lg3 += v[3];
            }
            const float mx = fmaxf(fmaxf(lg0, lg1), fmaxf(lg2, lg3));
            const float e0 = __expf(lg0 - mx), e1 = __expf(lg1 - mx);
            const float e2 = __expf(lg2 - mx), e3 = __expf(lg3 - mx);
            const float inv = __builtin_amdgcn_rcpf(e0 + e1 + e2 + e3);
            half2v wg2[4];
            {
                const float wf[4] = { e0 * inv, e1 * inv, e2 * inv, e3 * inv };
#pragma unroll
                for (int k = 0; k < 4; k++) {
                    const _Float16 h = (_Float16)wf[k];
                    half2v v2; v2[0] = h; v2[1] = h; wg2[k] = v2;
                }
            }
            half2v hn[4] = {};
#pragma unroll
            for (int k = 0; k < 4; k++) {
                const int slot = k * 32 + c32;
                UH ov;
                ov.h = *(const half8*)((const char*)outs_s + r_c * 2048 + ((slot ^ swzC) << 4));
#pragma unroll
                for (int pp = 0; pp < 4; pp++)
                    hn[pp] = hn[pp] + ov.h2[pp] * wg2[k];
            }
            UH ho;
#pragma unroll
            for (int pp = 0; pp < 4; pp++) ho.h2[pp] = hn[pp];
            *(uint4*)((char*)hh_s + r_c * 512 + ((c32 ^ swzC) << 4)) = ho.u;
        }
        if (t + 1 < Tn) {
            *(_Float16*)((char*)xs_s + xsb0) = (_Float16)xr0;
            if (has2) *(_Float16*)((char*)xs_s + xsb1) = (_Float16)xr1;
        }
        // loop-top BAR orders hh/xs writes vs next step's reads
    }

    BAR();
    // ---- final FC ----
    if (tid < ROWS * On) {
        const int r = tid >> 4, o = tid & 15;
        float s = b_fc[o];
#pragma unroll 4
        for (int j8 = 0; j8 < 32; j8++) {
            const half8 hv = *(const half8*)((const char*)hh_s + r * 512 + ((j8 ^ (r & 7)) << 4));
#pragma unroll
            for (int jj = 0; jj < 8; jj++)
                s = fmaf((float)hv[jj], W_fc[o * Hn + j8 * 8 + jj], s);
        }
        out[(size_t)(b0 + r) * On + o] = s;
    }
#undef ISSUE
}

extern "C" void kernel_launch(void* const* d_in, const int* in_sizes, int n_in,
                              void* d_out, int out_size, void* d_ws, size_t ws_size,
                              hipStream_t stream) {
    const float* x      = (const float*)d_in[0];
    const float* W_in   = (const float*)d_in[1];
    const float* b_in   = (const float*)d_in[2];
    const float* W_rec  = (const float*)d_in[3];
    const float* b_rec  = (const float*)d_in[4];
    const float* W_gate = (const float*)d_in[5];
    const float* b_gate = (const float*)d_in[6];
    const float* W_fc   = (const float*)d_in[7];
    const float* b_fc   = (const float*)d_in[8];
    float* out = (float*)d_out;

    _Float16* WPB = (_Float16*)d_ws;   // 640 frags * 1 KB = 640 KB

    pack_frags<<<640, 64, 0, stream>>>(W_rec, W_in, WPB);
    diru_reg2<<<NBLK, 512, 0, stream>>>(x, WPB, b_in, b_rec,
                                        W_gate, b_gate, W_fc, b_fc, out);
}